// Round 8
// baseline (1046.064 us; speedup 1.0000x reference)
//
#include <hip/hip_runtime.h>
#include <hip/hip_bf16.h>
#include <stdint.h>

#define N_SAM 10000
#define N_GEN 20000
#define DSAM  2000
#define DGEN  500
#define NB    8       // counting-sort chunks (small => long runs => low write amp)
#define NBNS  10240   // max LDS bins per slice (40 KB)

typedef __hip_bfloat16 bf16;
typedef short bf16x8 __attribute__((ext_vector_type(8)));
typedef float f32x4 __attribute__((ext_vector_type(4)));

__device__ __forceinline__ float bfbits2f(unsigned short u) {
    unsigned v = ((unsigned)u) << 16;
    return __builtin_bit_cast(float, v);
}
__device__ __forceinline__ unsigned short f2bfbits(float f) {
    bf16 h = __float2bfloat16(f);
    return __builtin_bit_cast(unsigned short, h);
}
__device__ __forceinline__ unsigned packbf2(float lo, float hi) {
    return ((unsigned)f2bfbits(lo)) | (((unsigned)f2bfbits(hi)) << 16);
}
// accumulate 8 bf16 (16 B) into a[0..7]
__device__ __forceinline__ void acc16(const unsigned short* p, float* a) {
    uint4 u = *reinterpret_cast<const uint4*>(p);
    a[0] += __builtin_bit_cast(float, u.x << 16);
    a[1] += __builtin_bit_cast(float, u.x & 0xffff0000u);
    a[2] += __builtin_bit_cast(float, u.y << 16);
    a[3] += __builtin_bit_cast(float, u.y & 0xffff0000u);
    a[4] += __builtin_bit_cast(float, u.z << 16);
    a[5] += __builtin_bit_cast(float, u.z & 0xffff0000u);
    a[6] += __builtin_bit_cast(float, u.w << 16);
    a[7] += __builtin_bit_cast(float, u.w & 0xffff0000u);
}

// ---------------------------------------------------------------------------
// Counting-sort phase 1: per-(block,bin) histograms, LDS-privatized.
// ---------------------------------------------------------------------------
__global__ __launch_bounds__(256) void hist_count_kernel(
    const int* __restrict__ ssg, const int* __restrict__ dsg,
    const int* __restrict__ sgs, const int* __restrict__ dgs,
    unsigned* __restrict__ cs_ssg, unsigned* __restrict__ cs_dsg,
    unsigned* __restrict__ cs_sgs, unsigned* __restrict__ cs_dgs,
    int ne, int chunk) {
    __shared__ unsigned bins[NBNS];
    const int* arr; unsigned* counts; int lo, hi, nb;
    switch (blockIdx.y) {
        case 0:  arr = ssg; counts = cs_ssg; lo = 0;     hi = 10000; nb = 10000; break;
        case 1:  arr = dsg; counts = cs_dsg; lo = 0;     hi = 10240; nb = 20000; break;
        case 2:  arr = dsg; counts = cs_dsg; lo = 10240; hi = 20000; nb = 20000; break;
        case 3:  arr = sgs; counts = cs_sgs; lo = 0;     hi = 10240; nb = 20000; break;
        case 4:  arr = sgs; counts = cs_sgs; lo = 10240; hi = 20000; nb = 20000; break;
        default: arr = dgs; counts = cs_dgs; lo = 0;     hi = 10000; nb = 10000; break;
    }
    int span = hi - lo;
    for (int i = threadIdx.x; i < span; i += 256) bins[i] = 0u;
    __syncthreads();
    int blk = blockIdx.x;
    int e0 = blk * chunk;
    int e1 = e0 + chunk; if (e1 > ne) e1 = ne;
    for (int e = e0 + threadIdx.x; e < e1; e += 256) {
        int b = arr[e];
        if (b >= lo && b < hi) atomicAdd(&bins[b - lo], 1u);
    }
    __syncthreads();
    unsigned* out = counts + (size_t)blk * nb + lo;
    for (int i = threadIdx.x; i < span; i += 256) out[i] = bins[i];
}

// ---------------------------------------------------------------------------
// Reduce per-block counts -> totals; fused degree normalizers rsqrt(max(d,1)).
// ---------------------------------------------------------------------------
__global__ __launch_bounds__(256) void reduce_counts_kernel(
    const unsigned* __restrict__ cs_ssg, const unsigned* __restrict__ cs_dsg,
    const unsigned* __restrict__ cs_sgs, const unsigned* __restrict__ cs_dgs,
    unsigned* __restrict__ cnt_dsg, unsigned* __restrict__ cnt_dgs,
    float* __restrict__ rs_out_sam, float* __restrict__ rs_in_gen,
    float* __restrict__ rs_out_gen, float* __restrict__ rs_in_sam) {
    int i = blockIdx.x * 256 + threadIdx.x;
    int which = blockIdx.y;
    const unsigned* cs; int nb;
    switch (which) {
        case 0:  cs = cs_ssg; nb = 10000; break;
        case 1:  cs = cs_dsg; nb = 20000; break;
        case 2:  cs = cs_sgs; nb = 20000; break;
        default: cs = cs_dgs; nb = 10000; break;
    }
    if (i >= nb) return;
    unsigned s = 0;
    #pragma unroll
    for (int b = 0; b < NB; b++) s += cs[(size_t)b * nb + i];
    unsigned c = (s < 1u) ? 1u : s;
    float r = rsqrtf((float)c);
    if (which == 0)      { rs_out_sam[i] = r; }
    else if (which == 1) { cnt_dsg[i] = s; rs_in_gen[i] = r; }
    else if (which == 2) { rs_out_gen[i] = r; }
    else                 { cnt_dgs[i] = s; rs_in_sam[i] = r; }
}

// ---------------------------------------------------------------------------
// Two exclusive scans in one launch (block 0 / block 1). row[n] = total.
// ---------------------------------------------------------------------------
__global__ __launch_bounds__(1024) void scan2_kernel(
    const unsigned* __restrict__ c0, unsigned* __restrict__ r0, int nA,
    const unsigned* __restrict__ c1, unsigned* __restrict__ r1, int nB) {
    const unsigned* cnt; unsigned* row; int n;
    if (blockIdx.x == 0) { cnt = c0; row = r0; n = nA; }
    else                 { cnt = c1; row = r1; n = nB; }
    __shared__ unsigned sdata[1024];
    __shared__ unsigned carry_s;
    int t = threadIdx.x;
    if (t == 0) carry_s = 0;
    __syncthreads();
    for (int base = 0; base < n; base += 1024) {
        int i = base + t;
        unsigned v = (i < n) ? cnt[i] : 0u;
        sdata[t] = v;
        __syncthreads();
        for (int off = 1; off < 1024; off <<= 1) {
            unsigned add = (t >= off) ? sdata[t - off] : 0u;
            __syncthreads();
            sdata[t] += add;
            __syncthreads();
        }
        unsigned incl = sdata[t];
        unsigned carry = carry_s;
        if (i < n) row[i] = carry + incl - v;
        __syncthreads();
        if (t == 1023) carry_s = carry + incl;
        __syncthreads();
    }
    if (t == 0) row[n] = carry_s;
}

// ---------------------------------------------------------------------------
// Per-(block,bin) starting cursors
// ---------------------------------------------------------------------------
__global__ __launch_bounds__(256) void cursor_kernel(
    const unsigned* __restrict__ cs_dsg, const unsigned* __restrict__ cs_dgs,
    const unsigned* __restrict__ row_sg, const unsigned* __restrict__ row_gs,
    unsigned* __restrict__ cur_sg_m, unsigned* __restrict__ cur_gs_m) {
    int i = blockIdx.x * 256 + threadIdx.x;
    const unsigned* cs; const unsigned* row; unsigned* cur; int nb;
    if (blockIdx.y == 0) { cs = cs_dsg; row = row_sg; cur = cur_sg_m; nb = 20000; }
    else                 { cs = cs_dgs; row = row_gs; cur = cur_gs_m; nb = 10000; }
    if (i >= nb) return;
    unsigned run = row[i];
    #pragma unroll
    for (int b = 0; b < NB; b++) {
        cur[(size_t)b * nb + i] = run;
        run += cs[(size_t)b * nb + i];
    }
}

// ---------------------------------------------------------------------------
// Counting-sort phase 2: place edges with LDS cursors (no global atomics).
// ---------------------------------------------------------------------------
__global__ __launch_bounds__(256) void scatter_sorted_kernel(
    const int* __restrict__ src_sg, const int* __restrict__ dst_sg,
    const int* __restrict__ src_gs, const int* __restrict__ dst_gs,
    const unsigned* __restrict__ cur_sg_m, const unsigned* __restrict__ cur_gs_m,
    int* __restrict__ col_sg, int* __restrict__ col_gs, int ne, int chunk) {
    __shared__ unsigned curs[NBNS];
    const int* src; const int* dst; const unsigned* cmat; int* col; int lo, hi, nb;
    switch (blockIdx.y) {
        case 0:  src = src_sg; dst = dst_sg; cmat = cur_sg_m; col = col_sg; lo = 0;     hi = 10240; nb = 20000; break;
        case 1:  src = src_sg; dst = dst_sg; cmat = cur_sg_m; col = col_sg; lo = 10240; hi = 20000; nb = 20000; break;
        default: src = src_gs; dst = dst_gs; cmat = cur_gs_m; col = col_gs; lo = 0;     hi = 10000; nb = 10000; break;
    }
    int span = hi - lo, blk = blockIdx.x;
    const unsigned* cin = cmat + (size_t)blk * nb + lo;
    for (int i = threadIdx.x; i < span; i += 256) curs[i] = cin[i];
    __syncthreads();
    int e0 = blk * chunk;
    int e1 = e0 + chunk; if (e1 > ne) e1 = ne;
    for (int e = e0 + threadIdx.x; e < e1; e += 256) {
        int d = dst[e];
        if (d >= lo && d < hi) {
            unsigned p = atomicAdd(&curs[d - lo], 1u);
            col[p] = src[e];
        }
    }
}

// ---------------------------------------------------------------------------
// Weight transpose+convert: W[K][N] fp32 -> WT[N][Kp] bf16, zero-pad [K,Kp)
// ---------------------------------------------------------------------------
struct WDesc { const float* src; unsigned short* dst; int K, N, Kp; };
struct WPack { WDesc d[8]; };

__global__ __launch_bounds__(256) void transpose_weights_kernel(WPack p) {
    WDesc d = p.d[blockIdx.z];
    int n  = blockIdx.x * 32 + threadIdx.x;
    int kp = blockIdx.y * 8 + threadIdx.y;
    if (n >= d.N || kp >= d.Kp) return;
    float v = (kp < d.K) ? d.src[(size_t)kp * d.N + n] : 0.0f;
    d.dst[(size_t)n * d.Kp + kp] = f2bfbits(v);
}

// ---------------------------------------------------------------------------
// MFMA bf16 GEMM, full-N tile (A fetched once): C[M][N] = A[M][K]*BT[N][Kp]^T
// with epilogue (+bias[col])(*rs[row]), bf16 out. N = NT*64. Block tile
// 64 x N; 4 waves as 2x2, wave tile 32 x (NT*32); BK=64; LDS pad 72.
// Two problem instances per launch via blockIdx.z (GPack2).
// ---------------------------------------------------------------------------
struct GDesc {
    const void* A; const unsigned short* BT;
    const float* bias; const float* rs;
    unsigned short* C; int M, K, Kp;
};
struct GPack2 { GDesc d[2]; };

template <typename AT, int NT>
__global__ __launch_bounds__(256) void gemm_mfma(GPack2 pk) {
    const GDesc g = pk.d[blockIdx.z];
    const int N = NT * 64;
    const int BKP = 72;
    __shared__ __attribute__((aligned(16))) unsigned short As[64][BKP];
    __shared__ __attribute__((aligned(16))) unsigned short Bs[64 * NT][BKP];
    int t = threadIdx.x;
    int m0 = blockIdx.y * 64;
    if (m0 >= g.M) return;  // uniform exit (merged grids)
    const AT* A = (const AT*)g.A;
    const unsigned short* BT = g.BT;
    const int M = g.M, K = g.K, Kp = g.Kp;

    int wave = t >> 6, lane = t & 63;
    int wm = (wave >> 1) * 32, wn = (wave & 1) * (NT * 32);
    int q = lane >> 4, mr = lane & 15;
    int lr = t >> 2, lk = (t & 3) * 16;
    int gm = m0 + lr;

    // B loader mapping: TPR threads per B row
    const int TPR = 256 / (64 * NT);           // 4 / 2 / 1
    int rB = t / TPR;
    int kB = (t % TPR) * (64 / TPR);           // shorts

    f32x4 acc[2][2 * NT] = {};

    for (int k0 = 0; k0 < Kp; k0 += 64) {
        // ---- stage A tile (64 x 64) ----
        {
            int gk = k0 + lk;
            if (gm < M && gk + 16 <= K) {
                if constexpr (sizeof(AT) == 4) {
                    const float* ap = (const float*)A + (size_t)gm * K + gk;
                    #pragma unroll
                    for (int c = 0; c < 4; c++) {
                        float4 u = *reinterpret_cast<const float4*>(ap + c * 4);
                        As[lr][lk + c * 4 + 0] = f2bfbits(u.x);
                        As[lr][lk + c * 4 + 1] = f2bfbits(u.y);
                        As[lr][lk + c * 4 + 2] = f2bfbits(u.z);
                        As[lr][lk + c * 4 + 3] = f2bfbits(u.w);
                    }
                } else {
                    const unsigned short* ap = (const unsigned short*)A + (size_t)gm * K + gk;
                    #pragma unroll
                    for (int c = 0; c < 4; c++)
                        *reinterpret_cast<ushort4*>(&As[lr][lk + c * 4]) =
                            *reinterpret_cast<const ushort4*>(ap + c * 4);
                }
            } else {
                #pragma unroll
                for (int j = 0; j < 16; j++) {
                    float v = 0.0f;
                    int k = gk + j;
                    if (gm < M && k < K) {
                        if constexpr (sizeof(AT) == 4) v = ((const float*)A)[(size_t)gm * K + k];
                        else v = bfbits2f(((const unsigned short*)A)[(size_t)gm * K + k]);
                    }
                    As[lr][lk + j] = f2bfbits(v);
                }
            }
        }
        // ---- stage B tile (N x 64; BT zero-padded to Kp) ----
        {
            const unsigned short* bp = BT + (size_t)rB * Kp + k0 + kB;
            #pragma unroll
            for (int c = 0; c < NT * 4; c++)
                *reinterpret_cast<ushort4*>(&Bs[rB][kB + c * 4]) =
                    *reinterpret_cast<const ushort4*>(bp + c * 4);
        }
        __syncthreads();
        // ---- compute ----
        #pragma unroll
        for (int kk = 0; kk < 64; kk += 32) {
            bf16x8 af[2], bfv[2 * NT];
            #pragma unroll
            for (int i = 0; i < 2; i++)
                af[i] = *reinterpret_cast<const bf16x8*>(&As[wm + i * 16 + mr][kk + q * 8]);
            #pragma unroll
            for (int j = 0; j < 2 * NT; j++)
                bfv[j] = *reinterpret_cast<const bf16x8*>(&Bs[wn + j * 16 + mr][kk + q * 8]);
            #pragma unroll
            for (int i = 0; i < 2; i++)
                #pragma unroll
                for (int j = 0; j < 2 * NT; j++)
                    acc[i][j] = __builtin_amdgcn_mfma_f32_16x16x32_bf16(af[i], bfv[j], acc[i][j], 0, 0, 0);
        }
        __syncthreads();
    }
    // ---- epilogue ----
    #pragma unroll
    for (int i = 0; i < 2; i++) {
        #pragma unroll
        for (int r = 0; r < 4; r++) {
            int row = m0 + wm + i * 16 + q * 4 + r;
            if (row >= M) continue;
            float sc = (g.rs != nullptr) ? g.rs[row] : 1.0f;
            #pragma unroll
            for (int j = 0; j < 2 * NT; j++) {
                int col = wn + j * 16 + mr;
                float v = acc[i][j][r];
                if (g.bias != nullptr) v += g.bias[col];
                v *= sc;
                g.C[(size_t)row * N + col] = f2bfbits(v);
            }
        }
    }
}

// ---------------------------------------------------------------------------
// CSR aggregation over bf16 P, MLP-optimized (16 B/lane, R edge slots,
// 2-deep unroll, shfl_down fold).
// ---------------------------------------------------------------------------
template <int VPL, bool OUTBF>
__global__ __launch_bounds__(256) void agg_csr_kernel(
    const unsigned* __restrict__ rowptr, const int* __restrict__ col,
    const unsigned short* __restrict__ P, const float* __restrict__ rs_in,
    const float* __restrict__ bias, const float* __restrict__ rs_next,
    float* __restrict__ outF, unsigned short* __restrict__ outB, int n_dst) {
    const int D = VPL * 64;
    const int LPR = VPL * 8;   // lanes per row (16 B each)
    const int R = 8 / VPL;     // edge slots per pass
    int wave = threadIdx.x >> 6;
    int lane = threadIdx.x & 63;
    int sub = lane / LPR;
    int li  = lane % LPR;
    int r = blockIdx.x * 4 + wave;
    if (r >= n_dst) return;

    unsigned e0 = rowptr[r], e1 = rowptr[r + 1];
    float accA[8] = {}, accB[8] = {};
    unsigned e = e0;
    for (; e + 2 * R <= e1; e += 2 * R) {
        int sA = col[e + sub];
        int sB = col[e + R + sub];
        acc16(P + (size_t)sA * D + li * 8, accA);
        acc16(P + (size_t)sB * D + li * 8, accB);
    }
    for (; e < e1; e += R) {
        unsigned idx = e + sub;
        if (idx < e1) {
            int s = col[idx];
            acc16(P + (size_t)s * D + li * 8, accA);
        }
    }
    #pragma unroll
    for (int j = 0; j < 8; j++) accA[j] += accB[j];
    #pragma unroll
    for (int off = 32; off >= LPR; off >>= 1) {
        #pragma unroll
        for (int j = 0; j < 8; j++) accA[j] += __shfl_down(accA[j], off);
    }
    if (sub == 0) {
        float rsv = rs_in[r];
        float res[8];
        #pragma unroll
        for (int j = 0; j < 8; j++) {
            float v = accA[j] * rsv + bias[li * 8 + j];
            res[j] = (v >= 0.f) ? v : 0.25f * v;
        }
        if constexpr (OUTBF) {
            float sn = rs_next[r];
            uint4 o;
            o.x = packbf2(res[0] * sn, res[1] * sn);
            o.y = packbf2(res[2] * sn, res[3] * sn);
            o.z = packbf2(res[4] * sn, res[5] * sn);
            o.w = packbf2(res[6] * sn, res[7] * sn);
            *reinterpret_cast<uint4*>(outB + (size_t)r * D + li * 8) = o;
        } else {
            float* op = outF + (size_t)r * D + li * 8;
            *reinterpret_cast<float4*>(op)     = make_float4(res[0], res[1], res[2], res[3]);
            *reinterpret_cast<float4*>(op + 4) = make_float4(res[4], res[5], res[6], res[7]);
        }
    }
}

// ---------------------------------------------------------------------------
// Launch
// ---------------------------------------------------------------------------
extern "C" void kernel_launch(void* const* d_in, const int* in_sizes, int n_in,
                              void* d_out, int out_size, void* d_ws, size_t ws_size,
                              hipStream_t stream) {
    const float* sam_feat = (const float*)d_in[0];
    const float* gen_feat = (const float*)d_in[1];
    const int* src_sg = (const int*)d_in[2];
    const int* dst_sg = (const int*)d_in[3];
    const int* src_gs = (const int*)d_in[4];
    const int* dst_gs = (const int*)d_in[5];
    const float* l1W = (const float*)d_in[6];
    const float* l1b = (const float*)d_in[7];
    const float* l2W = (const float*)d_in[8];
    const float* l2b = (const float*)d_in[9];
    const float* Wsg[3] = {(const float*)d_in[10], (const float*)d_in[14], (const float*)d_in[18]};
    const float* bsg[3] = {(const float*)d_in[11], (const float*)d_in[15], (const float*)d_in[19]};
    const float* Wgs[3] = {(const float*)d_in[12], (const float*)d_in[16], (const float*)d_in[20]};
    const float* bgs[3] = {(const float*)d_in[13], (const float*)d_in[17], (const float*)d_in[21]};
    const int NE = in_sizes[2];
    const int CHUNK = (NE + NB - 1) / NB;

    // ---- workspace carve ----
    char* base = (char*)d_ws;
    size_t off = 0;
    auto alloc = [&](size_t bytes) -> char* {
        char* p = base + off;
        off = (off + bytes + 255) & ~(size_t)255;
        return p;
    };
    unsigned* cs_ssg = (unsigned*)alloc((size_t)NB * N_SAM * 4);
    unsigned* cs_dsg = (unsigned*)alloc((size_t)NB * N_GEN * 4);
    unsigned* cs_sgs = (unsigned*)alloc((size_t)NB * N_GEN * 4);
    unsigned* cs_dgs = (unsigned*)alloc((size_t)NB * N_SAM * 4);
    unsigned* cnt_dsg = (unsigned*)alloc(N_GEN * 4);
    unsigned* cnt_dgs = (unsigned*)alloc(N_SAM * 4);
    unsigned* row_sg = (unsigned*)alloc((N_GEN + 1) * 4);
    unsigned* row_gs = (unsigned*)alloc((N_SAM + 1) * 4);
    unsigned* cur_sg_m = (unsigned*)alloc((size_t)NB * N_GEN * 4);
    unsigned* cur_gs_m = (unsigned*)alloc((size_t)NB * N_SAM * 4);
    float* rs_out_sam = (float*)alloc(N_SAM * 4);
    float* rs_in_sam  = (float*)alloc(N_SAM * 4);
    float* rs_out_gen = (float*)alloc(N_GEN * 4);
    float* rs_in_gen  = (float*)alloc(N_GEN * 4);
    int* col_sg = (int*)alloc((size_t)NE * 4);
    int* col_gs = (int*)alloc((size_t)NE * 4);
    unsigned short* hs = (unsigned short*)alloc((size_t)N_SAM * 256 * 2);
    unsigned short* hg = (unsigned short*)alloc((size_t)N_GEN * 256 * 2);
    unsigned short* ps = (unsigned short*)alloc((size_t)N_SAM * 256 * 2);
    unsigned short* pg = (unsigned short*)alloc((size_t)N_GEN * 256 * 2);
    const int KP1 = 2048, KP2 = 512;
    unsigned short* BT_l1 = (unsigned short*)alloc((size_t)256 * KP1 * 2);
    unsigned short* BT_l2 = (unsigned short*)alloc((size_t)256 * KP2 * 2);
    unsigned short* BT_sg[3], *BT_gs[3];
    const int LN[3] = {256, 128, 64};
    const int LK[3] = {256, 256, 128};
    for (int i = 0; i < 3; i++) {
        BT_sg[i] = (unsigned short*)alloc((size_t)LN[i] * LK[i] * 2);
        BT_gs[i] = (unsigned short*)alloc((size_t)LN[i] * LK[i] * 2);
    }
    (void)ws_size;

    // ---- graph preprocessing: atomic-free counting sort ----
    hist_count_kernel<<<dim3(NB, 6), 256, 0, stream>>>(
        src_sg, dst_sg, src_gs, dst_gs, cs_ssg, cs_dsg, cs_sgs, cs_dgs, NE, CHUNK);
    reduce_counts_kernel<<<dim3((N_GEN + 255) / 256, 4), 256, 0, stream>>>(
        cs_ssg, cs_dsg, cs_sgs, cs_dgs, cnt_dsg, cnt_dgs,
        rs_out_sam, rs_in_gen, rs_out_gen, rs_in_sam);
    scan2_kernel<<<2, 1024, 0, stream>>>(cnt_dsg, row_sg, N_GEN, cnt_dgs, row_gs, N_SAM);
    cursor_kernel<<<dim3((N_GEN + 255) / 256, 2), 256, 0, stream>>>(
        cs_dsg, cs_dgs, row_sg, row_gs, cur_sg_m, cur_gs_m);
    scatter_sorted_kernel<<<dim3(NB, 3), 256, 0, stream>>>(
        src_sg, dst_sg, src_gs, dst_gs, cur_sg_m, cur_gs_m, col_sg, col_gs, NE, CHUNK);

    // ---- weight transpose+convert ----
    WPack wp;
    wp.d[0] = {l1W,    BT_l1,    DSAM, 256, KP1};
    wp.d[1] = {l2W,    BT_l2,    DGEN, 256, KP2};
    wp.d[2] = {Wsg[0], BT_sg[0], 256, 256, 256};
    wp.d[3] = {Wgs[0], BT_gs[0], 256, 256, 256};
    wp.d[4] = {Wsg[1], BT_sg[1], 256, 128, 256};
    wp.d[5] = {Wgs[1], BT_gs[1], 256, 128, 256};
    wp.d[6] = {Wsg[2], BT_sg[2], 128, 64, 128};
    wp.d[7] = {Wgs[2], BT_gs[2], 128, 64, 128};
    transpose_weights_kernel<<<dim3(8, KP1 / 8, 8), dim3(32, 8), 0, stream>>>(wp);

    dim3 blk(256);
    const int GYB = (N_GEN + 63) / 64;  // 313 covers both (uniform early-exit)

    // ---- input projections (merged; epilogue (acc+bias)*rs_out) ----
    {
        GPack2 gp;
        gp.d[0] = {sam_feat, BT_l1, l1b, rs_out_sam, hs, N_SAM, DSAM, KP1};
        gp.d[1] = {gen_feat, BT_l2, l2b, rs_out_gen, hg, N_GEN, DGEN, KP2};
        gemm_mfma<float, 4><<<dim3(1, GYB, 2), blk, 0, stream>>>(gp);
    }

    // ---- layer 1: 256 -> 256 ----
    {
        GPack2 gp;
        gp.d[0] = {hs, BT_sg[0], nullptr, nullptr, ps, N_SAM, 256, 256};
        gp.d[1] = {hg, BT_gs[0], nullptr, nullptr, pg, N_GEN, 256, 256};
        gemm_mfma<unsigned short, 4><<<dim3(1, GYB, 2), blk, 0, stream>>>(gp);
    }
    agg_csr_kernel<4, true><<<(N_GEN + 3) / 4, blk, 0, stream>>>(
        row_sg, col_sg, ps, rs_in_gen, bsg[0], rs_out_gen, nullptr, hg, N_GEN);
    agg_csr_kernel<4, true><<<(N_SAM + 3) / 4, blk, 0, stream>>>(
        row_gs, col_gs, pg, rs_in_sam, bgs[0], rs_out_sam, nullptr, hs, N_SAM);

    // ---- layer 2: 256 -> 128 ----
    {
        GPack2 gp;
        gp.d[0] = {hs, BT_sg[1], nullptr, nullptr, ps, N_SAM, 256, 256};
        gp.d[1] = {hg, BT_gs[1], nullptr, nullptr, pg, N_GEN, 256, 256};
        gemm_mfma<unsigned short, 2><<<dim3(1, GYB, 2), blk, 0, stream>>>(gp);
    }
    agg_csr_kernel<2, true><<<(N_GEN + 3) / 4, blk, 0, stream>>>(
        row_sg, col_sg, ps, rs_in_gen, bsg[1], rs_out_gen, nullptr, hg, N_GEN);
    agg_csr_kernel<2, true><<<(N_SAM + 3) / 4, blk, 0, stream>>>(
        row_gs, col_gs, pg, rs_in_sam, bgs[1], rs_out_sam, nullptr, hs, N_SAM);

    // ---- layer 3: 128 -> 64, fp32 outputs straight into d_out ----
    {
        GPack2 gp;
        gp.d[0] = {hs, BT_sg[2], nullptr, nullptr, ps, N_SAM, 128, 128};
        gp.d[1] = {hg, BT_gs[2], nullptr, nullptr, pg, N_GEN, 128, 128};
        gemm_mfma<unsigned short, 1><<<dim3(1, GYB, 2), blk, 0, stream>>>(gp);
    }
    float* out_sam = (float*)d_out;
    float* out_gen = out_sam + (size_t)N_SAM * 64;
    agg_csr_kernel<1, false><<<(N_GEN + 3) / 4, blk, 0, stream>>>(
        row_sg, col_sg, ps, rs_in_gen, bsg[2], nullptr, out_gen, nullptr, N_GEN);
    agg_csr_kernel<1, false><<<(N_SAM + 3) / 4, blk, 0, stream>>>(
        row_gs, col_gs, pg, rs_in_sam, bgs[2], nullptr, out_sam, nullptr, N_SAM);
}

// Round 9
// 672.289 us; speedup vs baseline: 1.5560x; 1.5560x over previous
//
#include <hip/hip_runtime.h>
#include <hip/hip_bf16.h>
#include <stdint.h>

#define N_SAM 10000
#define N_GEN 20000
#define DSAM  2000
#define DGEN  500
#define NB    32      // counting-sort chunks (round-7 proven)
#define NBNS  10240   // max LDS bins per hist slice (40 KB)
#define SSPAN 2560    // scatter slice span (10 KB LDS, 12 slices -> 384 blocks)

typedef __hip_bfloat16 bf16;
typedef short bf16x8 __attribute__((ext_vector_type(8)));
typedef float f32x4 __attribute__((ext_vector_type(4)));

__device__ __forceinline__ float bfbits2f(unsigned short u) {
    unsigned v = ((unsigned)u) << 16;
    return __builtin_bit_cast(float, v);
}
__device__ __forceinline__ unsigned short f2bfbits(float f) {
    bf16 h = __float2bfloat16(f);
    return __builtin_bit_cast(unsigned short, h);
}
__device__ __forceinline__ unsigned packbf2(float lo, float hi) {
    return ((unsigned)f2bfbits(lo)) | (((unsigned)f2bfbits(hi)) << 16);
}
// accumulate 8 bf16 (16 B) into a[0..7]
__device__ __forceinline__ void acc16(const unsigned short* p, float* a) {
    uint4 u = *reinterpret_cast<const uint4*>(p);
    a[0] += __builtin_bit_cast(float, u.x << 16);
    a[1] += __builtin_bit_cast(float, u.x & 0xffff0000u);
    a[2] += __builtin_bit_cast(float, u.y << 16);
    a[3] += __builtin_bit_cast(float, u.y & 0xffff0000u);
    a[4] += __builtin_bit_cast(float, u.z << 16);
    a[5] += __builtin_bit_cast(float, u.z & 0xffff0000u);
    a[6] += __builtin_bit_cast(float, u.w << 16);
    a[7] += __builtin_bit_cast(float, u.w & 0xffff0000u);
}

// ---------------------------------------------------------------------------
// Counting-sort phase 1: per-(block,bin) histograms, LDS-privatized.
// ---------------------------------------------------------------------------
__global__ __launch_bounds__(256) void hist_count_kernel(
    const int* __restrict__ ssg, const int* __restrict__ dsg,
    const int* __restrict__ sgs, const int* __restrict__ dgs,
    unsigned* __restrict__ cs_ssg, unsigned* __restrict__ cs_dsg,
    unsigned* __restrict__ cs_sgs, unsigned* __restrict__ cs_dgs,
    int ne, int chunk) {
    __shared__ unsigned bins[NBNS];
    const int* arr; unsigned* counts; int lo, hi, nb;
    switch (blockIdx.y) {
        case 0:  arr = ssg; counts = cs_ssg; lo = 0;     hi = 10000; nb = 10000; break;
        case 1:  arr = dsg; counts = cs_dsg; lo = 0;     hi = 10240; nb = 20000; break;
        case 2:  arr = dsg; counts = cs_dsg; lo = 10240; hi = 20000; nb = 20000; break;
        case 3:  arr = sgs; counts = cs_sgs; lo = 0;     hi = 10240; nb = 20000; break;
        case 4:  arr = sgs; counts = cs_sgs; lo = 10240; hi = 20000; nb = 20000; break;
        default: arr = dgs; counts = cs_dgs; lo = 0;     hi = 10000; nb = 10000; break;
    }
    int span = hi - lo;
    for (int i = threadIdx.x; i < span; i += 256) bins[i] = 0u;
    __syncthreads();
    int blk = blockIdx.x;
    int e0 = blk * chunk;
    int e1 = e0 + chunk; if (e1 > ne) e1 = ne;
    for (int e = e0 + threadIdx.x; e < e1; e += 256) {
        int b = arr[e];
        if (b >= lo && b < hi) atomicAdd(&bins[b - lo], 1u);
    }
    __syncthreads();
    unsigned* out = counts + (size_t)blk * nb + lo;
    for (int i = threadIdx.x; i < span; i += 256) out[i] = bins[i];
}

// ---------------------------------------------------------------------------
// Reduce per-block counts -> totals; fused degree normalizers rsqrt(max(d,1)).
// ---------------------------------------------------------------------------
__global__ __launch_bounds__(256) void reduce_counts_kernel(
    const unsigned* __restrict__ cs_ssg, const unsigned* __restrict__ cs_dsg,
    const unsigned* __restrict__ cs_sgs, const unsigned* __restrict__ cs_dgs,
    unsigned* __restrict__ cnt_dsg, unsigned* __restrict__ cnt_dgs,
    float* __restrict__ rs_out_sam, float* __restrict__ rs_in_gen,
    float* __restrict__ rs_out_gen, float* __restrict__ rs_in_sam) {
    int i = blockIdx.x * 256 + threadIdx.x;
    int which = blockIdx.y;
    const unsigned* cs; int nb;
    switch (which) {
        case 0:  cs = cs_ssg; nb = 10000; break;
        case 1:  cs = cs_dsg; nb = 20000; break;
        case 2:  cs = cs_sgs; nb = 20000; break;
        default: cs = cs_dgs; nb = 10000; break;
    }
    if (i >= nb) return;
    unsigned s = 0;
    #pragma unroll 4
    for (int b = 0; b < NB; b++) s += cs[(size_t)b * nb + i];
    unsigned c = (s < 1u) ? 1u : s;
    float r = rsqrtf((float)c);
    if (which == 0)      { rs_out_sam[i] = r; }
    else if (which == 1) { cnt_dsg[i] = s; rs_in_gen[i] = r; }
    else if (which == 2) { rs_out_gen[i] = r; }
    else                 { cnt_dgs[i] = s; rs_in_sam[i] = r; }
}

// ---------------------------------------------------------------------------
// Two exclusive scans in one launch (block 0 / block 1). row[n] = total.
// ---------------------------------------------------------------------------
__global__ __launch_bounds__(1024) void scan2_kernel(
    const unsigned* __restrict__ c0, unsigned* __restrict__ r0, int nA,
    const unsigned* __restrict__ c1, unsigned* __restrict__ r1, int nB) {
    const unsigned* cnt; unsigned* row; int n;
    if (blockIdx.x == 0) { cnt = c0; row = r0; n = nA; }
    else                 { cnt = c1; row = r1; n = nB; }
    __shared__ unsigned sdata[1024];
    __shared__ unsigned carry_s;
    int t = threadIdx.x;
    if (t == 0) carry_s = 0;
    __syncthreads();
    for (int base = 0; base < n; base += 1024) {
        int i = base + t;
        unsigned v = (i < n) ? cnt[i] : 0u;
        sdata[t] = v;
        __syncthreads();
        for (int off = 1; off < 1024; off <<= 1) {
            unsigned add = (t >= off) ? sdata[t - off] : 0u;
            __syncthreads();
            sdata[t] += add;
            __syncthreads();
        }
        unsigned incl = sdata[t];
        unsigned carry = carry_s;
        if (i < n) row[i] = carry + incl - v;
        __syncthreads();
        if (t == 1023) carry_s = carry + incl;
        __syncthreads();
    }
    if (t == 0) row[n] = carry_s;
}

// ---------------------------------------------------------------------------
// Per-(block,bin) starting cursors
// ---------------------------------------------------------------------------
__global__ __launch_bounds__(256) void cursor_kernel(
    const unsigned* __restrict__ cs_dsg, const unsigned* __restrict__ cs_dgs,
    const unsigned* __restrict__ row_sg, const unsigned* __restrict__ row_gs,
    unsigned* __restrict__ cur_sg_m, unsigned* __restrict__ cur_gs_m) {
    int i = blockIdx.x * 256 + threadIdx.x;
    const unsigned* cs; const unsigned* row; unsigned* cur; int nb;
    if (blockIdx.y == 0) { cs = cs_dsg; row = row_sg; cur = cur_sg_m; nb = 20000; }
    else                 { cs = cs_dgs; row = row_gs; cur = cur_gs_m; nb = 10000; }
    if (i >= nb) return;
    unsigned run = row[i];
    for (int b = 0; b < NB; b++) {
        cur[(size_t)b * nb + i] = run;
        run += cs[(size_t)b * nb + i];
    }
}

// ---------------------------------------------------------------------------
// Counting-sort phase 2: place edges with LDS cursors (no global atomics).
// 12 fine slices (SSPAN bins) x NB chunks = 384 blocks for latency hiding.
// Slices 0..7: sam->gen edges (dst range 20000); 8..11: gen->sam (10000).
// ---------------------------------------------------------------------------
__global__ __launch_bounds__(256) void scatter_sorted_kernel(
    const int* __restrict__ src_sg, const int* __restrict__ dst_sg,
    const int* __restrict__ src_gs, const int* __restrict__ dst_gs,
    const unsigned* __restrict__ cur_sg_m, const unsigned* __restrict__ cur_gs_m,
    int* __restrict__ col_sg, int* __restrict__ col_gs, int ne, int chunk) {
    __shared__ unsigned curs[SSPAN];
    int sl = blockIdx.y;
    const int* src; const int* dst; const unsigned* cmat; int* col; int lo, hi, nb;
    if (sl < 8) {
        src = src_sg; dst = dst_sg; cmat = cur_sg_m; col = col_sg; nb = 20000;
        lo = sl * SSPAN; hi = lo + SSPAN; if (hi > 20000) hi = 20000;
    } else {
        src = src_gs; dst = dst_gs; cmat = cur_gs_m; col = col_gs; nb = 10000;
        lo = (sl - 8) * SSPAN; hi = lo + SSPAN; if (hi > 10000) hi = 10000;
    }
    int span = hi - lo, blk = blockIdx.x;
    const unsigned* cin = cmat + (size_t)blk * nb + lo;
    for (int i = threadIdx.x; i < span; i += 256) curs[i] = cin[i];
    __syncthreads();
    int e0 = blk * chunk;
    int e1 = e0 + chunk; if (e1 > ne) e1 = ne;
    for (int e = e0 + threadIdx.x; e < e1; e += 256) {
        int d = dst[e];
        if (d >= lo && d < hi) {
            unsigned p = atomicAdd(&curs[d - lo], 1u);
            col[p] = src[e];
        }
    }
}

// ---------------------------------------------------------------------------
// Weight transpose+convert: W[K][N] fp32 -> WT[N][Kp] bf16, zero-pad [K,Kp)
// ---------------------------------------------------------------------------
struct WDesc { const float* src; unsigned short* dst; int K, N, Kp; };
struct WPack { WDesc d[8]; };

__global__ __launch_bounds__(256) void transpose_weights_kernel(WPack p) {
    WDesc d = p.d[blockIdx.z];
    int n  = blockIdx.x * 32 + threadIdx.x;
    int kp = blockIdx.y * 8 + threadIdx.y;
    if (n >= d.N || kp >= d.Kp) return;
    float v = (kp < d.K) ? d.src[(size_t)kp * d.N + n] : 0.0f;
    d.dst[(size_t)n * d.Kp + kp] = f2bfbits(v);
}

// ---------------------------------------------------------------------------
// MFMA bf16 GEMM (round-7 proven body): C[M][N](bf16) = A[M][K]*BT[N][Kp]^T,
// epilogue (+bias[col])(*rs[row]). Tile 64x64, 4 waves, BK=64, LDS pad 72.
// NEW: 1-D grid with XCD-aware swizzle — block i: x=i&7 (XCD), g=i>>3,
// ntile=g%GX, mtile=(g/GX)*8+x. All n-tiles of an m-row land on one XCD
// (round-robin dispatch) so each A row is fetched through exactly one L2.
// ---------------------------------------------------------------------------
template <typename AT>
__global__ __launch_bounds__(256) void gemm_mfma(
    const AT* __restrict__ A, const unsigned short* __restrict__ BT,
    const float* __restrict__ bias, const float* __restrict__ rs,
    unsigned short* __restrict__ C, int M, int N, int K, int Kp,
    int GX, int GY) {
    int bi = blockIdx.x;
    int xcd = bi & 7, g = bi >> 3;
    int ntile = g % GX;
    int mtile = (g / GX) * 8 + xcd;
    if (mtile >= GY) return;
    int m0 = mtile * 64, n0 = ntile * 64;

    const int BKP = 72;
    __shared__ __attribute__((aligned(16))) unsigned short As[64][BKP];
    __shared__ __attribute__((aligned(16))) unsigned short Bs[64][BKP];
    int t = threadIdx.x;
    int wave = t >> 6, lane = t & 63;
    int wm = (wave >> 1) * 32, wn = (wave & 1) * 32;
    int q = lane >> 4, mr = lane & 15;
    int lr = t >> 2, lk = (t & 3) * 16;
    int gm = m0 + lr;

    f32x4 acc[2][2] = {};

    for (int k0 = 0; k0 < Kp; k0 += 64) {
        {
            int gk = k0 + lk;
            if (gm < M && gk + 16 <= K) {
                if constexpr (sizeof(AT) == 4) {
                    const float* ap = (const float*)A + (size_t)gm * K + gk;
                    #pragma unroll
                    for (int c = 0; c < 4; c++) {
                        float4 u = *reinterpret_cast<const float4*>(ap + c * 4);
                        As[lr][lk + c * 4 + 0] = f2bfbits(u.x);
                        As[lr][lk + c * 4 + 1] = f2bfbits(u.y);
                        As[lr][lk + c * 4 + 2] = f2bfbits(u.z);
                        As[lr][lk + c * 4 + 3] = f2bfbits(u.w);
                    }
                } else {
                    const unsigned short* ap = (const unsigned short*)A + (size_t)gm * K + gk;
                    #pragma unroll
                    for (int c = 0; c < 4; c++)
                        *reinterpret_cast<ushort4*>(&As[lr][lk + c * 4]) =
                            *reinterpret_cast<const ushort4*>(ap + c * 4);
                }
            } else {
                #pragma unroll
                for (int j = 0; j < 16; j++) {
                    float v = 0.0f;
                    int k = gk + j;
                    if (gm < M && k < K) {
                        if constexpr (sizeof(AT) == 4) v = ((const float*)A)[(size_t)gm * K + k];
                        else v = bfbits2f(((const unsigned short*)A)[(size_t)gm * K + k]);
                    }
                    As[lr][lk + j] = f2bfbits(v);
                }
            }
        }
        {
            const unsigned short* bp = BT + (size_t)(n0 + lr) * Kp + k0 + lk;
            #pragma unroll
            for (int c = 0; c < 4; c++)
                *reinterpret_cast<ushort4*>(&Bs[lr][lk + c * 4]) =
                    *reinterpret_cast<const ushort4*>(bp + c * 4);
        }
        __syncthreads();
        #pragma unroll
        for (int kk = 0; kk < 64; kk += 32) {
            bf16x8 af[2], bf[2];
            #pragma unroll
            for (int i = 0; i < 2; i++)
                af[i] = *reinterpret_cast<const bf16x8*>(&As[wm + i * 16 + mr][kk + q * 8]);
            #pragma unroll
            for (int j = 0; j < 2; j++)
                bf[j] = *reinterpret_cast<const bf16x8*>(&Bs[wn + j * 16 + mr][kk + q * 8]);
            #pragma unroll
            for (int i = 0; i < 2; i++)
                #pragma unroll
                for (int j = 0; j < 2; j++)
                    acc[i][j] = __builtin_amdgcn_mfma_f32_16x16x32_bf16(af[i], bf[j], acc[i][j], 0, 0, 0);
        }
        __syncthreads();
    }
    #pragma unroll
    for (int i = 0; i < 2; i++) {
        #pragma unroll
        for (int r = 0; r < 4; r++) {
            int row = m0 + wm + i * 16 + q * 4 + r;
            if (row >= M) continue;
            float sc = (rs != nullptr) ? rs[row] : 1.0f;
            #pragma unroll
            for (int j = 0; j < 2; j++) {
                int col = n0 + wn + j * 16 + mr;
                float v = acc[i][j][r];
                if (bias != nullptr) v += bias[col];
                v *= sc;
                C[(size_t)row * N + col] = f2bfbits(v);
            }
        }
    }
}

// ---------------------------------------------------------------------------
// CSR aggregation over bf16 P, MLP-optimized (round-7 proven).
// ---------------------------------------------------------------------------
template <int VPL, bool OUTBF>
__global__ __launch_bounds__(256) void agg_csr_kernel(
    const unsigned* __restrict__ rowptr, const int* __restrict__ col,
    const unsigned short* __restrict__ P, const float* __restrict__ rs_in,
    const float* __restrict__ bias, const float* __restrict__ rs_next,
    float* __restrict__ outF, unsigned short* __restrict__ outB, int n_dst) {
    const int D = VPL * 64;
    const int LPR = VPL * 8;   // lanes per row (16 B each)
    const int R = 8 / VPL;     // edge slots per pass
    int wave = threadIdx.x >> 6;
    int lane = threadIdx.x & 63;
    int sub = lane / LPR;
    int li  = lane % LPR;
    int r = blockIdx.x * 4 + wave;
    if (r >= n_dst) return;

    unsigned e0 = rowptr[r], e1 = rowptr[r + 1];
    float accA[8] = {}, accB[8] = {};
    unsigned e = e0;
    for (; e + 2 * R <= e1; e += 2 * R) {
        int sA = col[e + sub];
        int sB = col[e + R + sub];
        acc16(P + (size_t)sA * D + li * 8, accA);
        acc16(P + (size_t)sB * D + li * 8, accB);
    }
    for (; e < e1; e += R) {
        unsigned idx = e + sub;
        if (idx < e1) {
            int s = col[idx];
            acc16(P + (size_t)s * D + li * 8, accA);
        }
    }
    #pragma unroll
    for (int j = 0; j < 8; j++) accA[j] += accB[j];
    #pragma unroll
    for (int off = 32; off >= LPR; off >>= 1) {
        #pragma unroll
        for (int j = 0; j < 8; j++) accA[j] += __shfl_down(accA[j], off);
    }
    if (sub == 0) {
        float rsv = rs_in[r];
        float res[8];
        #pragma unroll
        for (int j = 0; j < 8; j++) {
            float v = accA[j] * rsv + bias[li * 8 + j];
            res[j] = (v >= 0.f) ? v : 0.25f * v;
        }
        if constexpr (OUTBF) {
            float sn = rs_next[r];
            uint4 o;
            o.x = packbf2(res[0] * sn, res[1] * sn);
            o.y = packbf2(res[2] * sn, res[3] * sn);
            o.z = packbf2(res[4] * sn, res[5] * sn);
            o.w = packbf2(res[6] * sn, res[7] * sn);
            *reinterpret_cast<uint4*>(outB + (size_t)r * D + li * 8) = o;
        } else {
            float* op = outF + (size_t)r * D + li * 8;
            *reinterpret_cast<float4*>(op)     = make_float4(res[0], res[1], res[2], res[3]);
            *reinterpret_cast<float4*>(op + 4) = make_float4(res[4], res[5], res[6], res[7]);
        }
    }
}

// ---------------------------------------------------------------------------
// Launch
// ---------------------------------------------------------------------------
extern "C" void kernel_launch(void* const* d_in, const int* in_sizes, int n_in,
                              void* d_out, int out_size, void* d_ws, size_t ws_size,
                              hipStream_t stream) {
    const float* sam_feat = (const float*)d_in[0];
    const float* gen_feat = (const float*)d_in[1];
    const int* src_sg = (const int*)d_in[2];
    const int* dst_sg = (const int*)d_in[3];
    const int* src_gs = (const int*)d_in[4];
    const int* dst_gs = (const int*)d_in[5];
    const float* l1W = (const float*)d_in[6];
    const float* l1b = (const float*)d_in[7];
    const float* l2W = (const float*)d_in[8];
    const float* l2b = (const float*)d_in[9];
    const float* Wsg[3] = {(const float*)d_in[10], (const float*)d_in[14], (const float*)d_in[18]};
    const float* bsg[3] = {(const float*)d_in[11], (const float*)d_in[15], (const float*)d_in[19]};
    const float* Wgs[3] = {(const float*)d_in[12], (const float*)d_in[16], (const float*)d_in[20]};
    const float* bgs[3] = {(const float*)d_in[13], (const float*)d_in[17], (const float*)d_in[21]};
    const int NE = in_sizes[2];
    const int CHUNK = (NE + NB - 1) / NB;

    // ---- workspace carve ----
    char* base = (char*)d_ws;
    size_t off = 0;
    auto alloc = [&](size_t bytes) -> char* {
        char* p = base + off;
        off = (off + bytes + 255) & ~(size_t)255;
        return p;
    };
    unsigned* cs_ssg = (unsigned*)alloc((size_t)NB * N_SAM * 4);
    unsigned* cs_dsg = (unsigned*)alloc((size_t)NB * N_GEN * 4);
    unsigned* cs_sgs = (unsigned*)alloc((size_t)NB * N_GEN * 4);
    unsigned* cs_dgs = (unsigned*)alloc((size_t)NB * N_SAM * 4);
    unsigned* cnt_dsg = (unsigned*)alloc(N_GEN * 4);
    unsigned* cnt_dgs = (unsigned*)alloc(N_SAM * 4);
    unsigned* row_sg = (unsigned*)alloc((N_GEN + 1) * 4);
    unsigned* row_gs = (unsigned*)alloc((N_SAM + 1) * 4);
    unsigned* cur_sg_m = (unsigned*)alloc((size_t)NB * N_GEN * 4);
    unsigned* cur_gs_m = (unsigned*)alloc((size_t)NB * N_SAM * 4);
    float* rs_out_sam = (float*)alloc(N_SAM * 4);
    float* rs_in_sam  = (float*)alloc(N_SAM * 4);
    float* rs_out_gen = (float*)alloc(N_GEN * 4);
    float* rs_in_gen  = (float*)alloc(N_GEN * 4);
    int* col_sg = (int*)alloc((size_t)NE * 4);
    int* col_gs = (int*)alloc((size_t)NE * 4);
    unsigned short* hs = (unsigned short*)alloc((size_t)N_SAM * 256 * 2);
    unsigned short* hg = (unsigned short*)alloc((size_t)N_GEN * 256 * 2);
    unsigned short* ps = (unsigned short*)alloc((size_t)N_SAM * 256 * 2);
    unsigned short* pg = (unsigned short*)alloc((size_t)N_GEN * 256 * 2);
    const int KP1 = 2048, KP2 = 512;
    unsigned short* BT_l1 = (unsigned short*)alloc((size_t)256 * KP1 * 2);
    unsigned short* BT_l2 = (unsigned short*)alloc((size_t)256 * KP2 * 2);
    unsigned short* BT_sg[3], *BT_gs[3];
    const int LN[3] = {256, 128, 64};
    const int LK[3] = {256, 256, 128};
    for (int i = 0; i < 3; i++) {
        BT_sg[i] = (unsigned short*)alloc((size_t)LN[i] * LK[i] * 2);
        BT_gs[i] = (unsigned short*)alloc((size_t)LN[i] * LK[i] * 2);
    }
    (void)ws_size;

    // ---- graph preprocessing: atomic-free counting sort ----
    hist_count_kernel<<<dim3(NB, 6), 256, 0, stream>>>(
        src_sg, dst_sg, src_gs, dst_gs, cs_ssg, cs_dsg, cs_sgs, cs_dgs, NE, CHUNK);
    reduce_counts_kernel<<<dim3((N_GEN + 255) / 256, 4), 256, 0, stream>>>(
        cs_ssg, cs_dsg, cs_sgs, cs_dgs, cnt_dsg, cnt_dgs,
        rs_out_sam, rs_in_gen, rs_out_gen, rs_in_sam);
    scan2_kernel<<<2, 1024, 0, stream>>>(cnt_dsg, row_sg, N_GEN, cnt_dgs, row_gs, N_SAM);
    cursor_kernel<<<dim3((N_GEN + 255) / 256, 2), 256, 0, stream>>>(
        cs_dsg, cs_dgs, row_sg, row_gs, cur_sg_m, cur_gs_m);
    scatter_sorted_kernel<<<dim3(NB, 12), 256, 0, stream>>>(
        src_sg, dst_sg, src_gs, dst_gs, cur_sg_m, cur_gs_m, col_sg, col_gs, NE, CHUNK);

    // ---- weight transpose+convert ----
    WPack wp;
    wp.d[0] = {l1W,    BT_l1,    DSAM, 256, KP1};
    wp.d[1] = {l2W,    BT_l2,    DGEN, 256, KP2};
    wp.d[2] = {Wsg[0], BT_sg[0], 256, 256, 256};
    wp.d[3] = {Wgs[0], BT_gs[0], 256, 256, 256};
    wp.d[4] = {Wsg[1], BT_sg[1], 256, 128, 256};
    wp.d[5] = {Wgs[1], BT_gs[1], 256, 128, 256};
    wp.d[6] = {Wsg[2], BT_sg[2], 128, 64, 128};
    wp.d[7] = {Wgs[2], BT_gs[2], 128, 64, 128};
    transpose_weights_kernel<<<dim3(8, KP1 / 8, 8), dim3(32, 8), 0, stream>>>(wp);

    dim3 blk(256);
    const int GY_SAM = (N_SAM + 63) / 64;  // 157
    const int GY_GEN = (N_GEN + 63) / 64;  // 313
    // swizzled 1-D grid size: 8 * GX * ceil(GY/8)
    auto swgrid = [](int GX, int GY) { return 8 * GX * ((GY + 7) / 8); };

    // ---- input projections (epilogue: (acc+bias)*rs_out -> pre-scaled H) ----
    gemm_mfma<float><<<swgrid(4, GY_SAM), blk, 0, stream>>>(
        sam_feat, BT_l1, l1b, rs_out_sam, hs, N_SAM, 256, DSAM, KP1, 4, GY_SAM);
    gemm_mfma<float><<<swgrid(4, GY_GEN), blk, 0, stream>>>(
        gen_feat, BT_l2, l2b, rs_out_gen, hg, N_GEN, 256, DGEN, KP2, 4, GY_GEN);

    // ---- layer 1: 256 -> 256 ----
    gemm_mfma<unsigned short><<<swgrid(4, GY_SAM), blk, 0, stream>>>(
        hs, BT_sg[0], nullptr, nullptr, ps, N_SAM, 256, 256, 256, 4, GY_SAM);
    gemm_mfma<unsigned short><<<swgrid(4, GY_GEN), blk, 0, stream>>>(
        hg, BT_gs[0], nullptr, nullptr, pg, N_GEN, 256, 256, 256, 4, GY_GEN);
    agg_csr_kernel<4, true><<<(N_GEN + 3) / 4, blk, 0, stream>>>(
        row_sg, col_sg, ps, rs_in_gen, bsg[0], rs_out_gen, nullptr, hg, N_GEN);
    agg_csr_kernel<4, true><<<(N_SAM + 3) / 4, blk, 0, stream>>>(
        row_gs, col_gs, pg, rs_in_sam, bgs[0], rs_out_sam, nullptr, hs, N_SAM);

    // ---- layer 2: 256 -> 128 ----
    gemm_mfma<unsigned short><<<swgrid(2, GY_SAM), blk, 0, stream>>>(
        hs, BT_sg[1], nullptr, nullptr, ps, N_SAM, 128, 256, 256, 2, GY_SAM);
    gemm_mfma<unsigned short><<<swgrid(2, GY_GEN), blk, 0, stream>>>(
        hg, BT_gs[1], nullptr, nullptr, pg, N_GEN, 128, 256, 256, 2, GY_GEN);
    agg_csr_kernel<2, true><<<(N_GEN + 3) / 4, blk, 0, stream>>>(
        row_sg, col_sg, ps, rs_in_gen, bsg[1], rs_out_gen, nullptr, hg, N_GEN);
    agg_csr_kernel<2, true><<<(N_SAM + 3) / 4, blk, 0, stream>>>(
        row_gs, col_gs, pg, rs_in_sam, bgs[1], rs_out_sam, nullptr, hs, N_SAM);

    // ---- layer 3: 128 -> 64, fp32 outputs straight into d_out ----
    gemm_mfma<unsigned short><<<swgrid(1, GY_SAM), blk, 0, stream>>>(
        hs, BT_sg[2], nullptr, nullptr, ps, N_SAM, 64, 128, 128, 1, GY_SAM);
    gemm_mfma<unsigned short><<<swgrid(1, GY_GEN), blk, 0, stream>>>(
        hg, BT_gs[2], nullptr, nullptr, pg, N_GEN, 64, 128, 128, 1, GY_GEN);
    float* out_sam = (float*)d_out;
    float* out_gen = out_sam + (size_t)N_SAM * 64;
    agg_csr_kernel<1, false><<<(N_GEN + 3) / 4, blk, 0, stream>>>(
        row_sg, col_sg, ps, rs_in_gen, bsg[2], nullptr, out_gen, nullptr, N_GEN);
    agg_csr_kernel<1, false><<<(N_SAM + 3) / 4, blk, 0, stream>>>(
        row_gs, col_gs, pg, rs_in_sam, bgs[2], nullptr, out_sam, nullptr, N_SAM);
}